// Round 4
// baseline (83.595 us; speedup 1.0000x reference)
//
#include <hip/hip_runtime.h>
#include <hip/hip_fp16.h>

#define NUM_VARS    10000
#define NUM_CLAUSES 100000
#define BATCH       256
#define CPI         4                     // clauses per chunk (12 gathers)
#define NCHUNK      (NUM_CLAUSES / CPI)   // 25000 exact
#define WAVES_H     2048                  // waves per batch-half (grid 512x512)
#define UNROLL_CH   12                    // static chunks/wave; +1 conditional tail

typedef __attribute__((ext_vector_type(4))) _Float16 half4_t;
typedef __attribute__((ext_vector_type(2))) _Float16 half2_t;
typedef __attribute__((ext_vector_type(4))) float    float4_t;

static __device__ __forceinline__ half2_t h2max(half2_t a, half2_t b) {
    half2_t r;                       // v_pk_max_f16 (no NaN in this data)
    r.x = (a.x > b.x) ? a.x : b.x;
    r.y = (a.y > b.y) ? a.y : b.y;
    return r;
}
static __device__ __forceinline__ half2_t h2min(half2_t a, half2_t b) {
    half2_t r;                       // v_pk_min_f16
    r.x = (a.x < b.x) ? a.x : b.x;
    r.y = (a.y < b.y) ? a.y : b.y;
    return r;
}
// neg ? 1-x : x  ==  s*x + n, s=1-2n in {+1,-1}: one v_pk_fma_f16; neg is
// wave-uniform so s,n build scalar-side (s_cselect).
static __device__ __forceinline__ half2_t litval(half2_t x, int neg) {
    const _Float16 s = neg ? (_Float16)-1.0f : (_Float16)1.0f;
    const _Float16 n = neg ? (_Float16)1.0f  : (_Float16)0.0f;
    half2_t sv; sv.x = s; sv.y = s;
    half2_t nv; nv.x = n; nv.y = n;
    return x * sv + nv;
}

// Pipeline bank: one chunk's metadata (uniform -> SGPR) + gather data.
struct Bank {
    int     idx[CPI * 3];
    int     neg[CPI * 3];
    half2_t g  [CPI * 3];
};

static __device__ __forceinline__ void loadMeta(Bank& b,
        const int* __restrict__ lit_idx, const int* __restrict__ lit_neg,
        int ch) {
    const int base = ch * (CPI * 3);    // 48B-aligned -> s_load_dwordx8/x4
    #pragma unroll
    for (int j = 0; j < CPI * 3; ++j) b.idx[j] = lit_idx[base + j];
    #pragma unroll
    for (int j = 0; j < CPI * 3; ++j) b.neg[j] = lit_neg[base + j];
}
static __device__ __forceinline__ void issueG(Bank& b,
        const half2_t* __restrict__ in, int coff) {
    #pragma unroll
    for (int j = 0; j < CPI * 3; ++j)
        b.g[j] = in[(b.idx[j] << 7) + coff];   // 256B/wave, L2-resident
}
static __device__ __forceinline__ void computeC(Bank& b, half2_t& acc) {
    #pragma unroll
    for (int q = 0; q < CPI; ++q) {
        const half2_t v0 = litval(b.g[3*q+0], b.neg[3*q+0]);
        const half2_t v1 = litval(b.g[3*q+1], b.neg[3*q+1]);
        const half2_t v2 = litval(b.g[3*q+2], b.neg[3*q+2]);
        acc = h2min(acc, h2max(h2max(v0, v1), v2));
    }
}

// Kernel 1: fp32 -> fp16 convert into d_ws + init d_out to +inf.
// The harness's 256 MiB ws poison fill is UNCONDITIONAL (r1/r2: fills ran
// at ~41us/call with ws untouched), so using ws costs nothing extra.
__global__ __launch_bounds__(256) void fuzzy_convert_init(
    const float4_t* __restrict__ in,    // [NUM_VARS*BATCH/4] fp32
    half4_t*        __restrict__ out16, // same linear layout, fp16
    float*          __restrict__ out)   // [BATCH]
{
    if (blockIdx.x == 0 && threadIdx.x < BATCH)
        out[threadIdx.x] = __uint_as_float(0x7F800000u);  // +inf

    const int n4 = NUM_VARS * BATCH / 4;  // 640000
    for (int i = blockIdx.x * blockDim.x + threadIdx.x; i < n4;
         i += gridDim.x * blockDim.x) {
        float4_t v = in[i];
        half4_t h;
        h.x = (_Float16)v.x;  h.y = (_Float16)v.y;
        h.z = (_Float16)v.z;  h.w = (_Float16)v.w;
        out16[i] = h;
    }
}

// Batch-half split with XCD steering (fp16 footprint/half = 2.56MB < 4MiB
// per-XCD L2). r3 showed the chunk loop is latency-bound, not BW-bound:
// each iteration serialized {s_load meta -> gathers -> vmcnt(0) -> compute}.
// This version is a 2-deep static software pipeline: per phase we
//   issue gathers(chunk k) ; compute(chunk k-1) [vmcnt counts: its 12 loads
//   have been in flight one full phase] ; s_load meta(chunk k+1) into the
//   bank compute just freed.
// All bank indices compile-time constant (full unroll) -> registers.
__global__ __launch_bounds__(512, 4) void fuzzy_cnf_fp16(
    const half2_t* __restrict__ input16,  // [NUM_VARS, 128] half2
    const int*     __restrict__ lit_idx,  // [NUM_CLAUSES, 3]
    const int*     __restrict__ lit_neg,  // [NUM_CLAUSES, 3]
    float*         __restrict__ out)      // [BATCH]
{
    const int wave   = threadIdx.x >> 6;            // 0..7
    const int lane   = threadIdx.x & 63;
    const int xcd    = blockIdx.x & 7;              // round-robin heuristic
    const int half   = (xcd >= 4) ? 1 : 0;          // batch half
    const int hBlock = ((blockIdx.x >> 3) << 2) | (xcd & 3);       // 0..255
    const int gwave  = __builtin_amdgcn_readfirstlane(hBlock * 8 + wave); // 0..2047
    const int coff   = half * 64 + lane;            // half2 column index

    half2_t acc;
    acc.x = (_Float16)30000.0f;  acc.y = (_Float16)30000.0f;

    Bank A, B;
    const int c = gwave;                            // chunk k lives at c + k*W

    // prologue: chunk0 meta+gathers in flight, chunk1 meta in flight
    loadMeta(A, lit_idx, lit_neg, c);
    issueG(A, input16, coff);
    loadMeta(B, lit_idx, lit_neg, c + WAVES_H);

    // steady state, fully unrolled: phase k = 1..11
    #pragma unroll
    for (int k = 1; k < UNROLL_CH; ++k) {
        Bank& cur = (k & 1) ? B : A;                // chunk k   (constant-folded)
        Bank& prv = (k & 1) ? A : B;                // chunk k-1
        issueG(cur, input16, coff);                 // 12 more loads in flight
        computeC(prv, acc);                         // waits only chunk k-1's loads
        if (k + 1 < UNROLL_CH)                      // constant-folded
            loadMeta(prv, lit_idx, lit_neg, c + (k + 1) * WAVES_H);
    }
    computeC((UNROLL_CH - 1) & 1 ? B : A, acc);     // chunk 11

    // ragged tail: 25000 = 12*2048 + 424 -> waves with gwave<424 do chunk 12
    if (c + UNROLL_CH * WAVES_H < NCHUNK) {
        loadMeta(A, lit_idx, lit_neg, c + UNROLL_CH * WAVES_H);
        issueG(A, input16, coff);
        computeC(A, acc);
    }

    // 8 waves -> partial min per column in LDS, then one device atomicMin per
    // column per block (values >= 0 so float-bit order == uint order).
    __shared__ float sm[8][128];
    sm[wave][lane * 2 + 0] = (float)acc.x;
    sm[wave][lane * 2 + 1] = (float)acc.y;
    __syncthreads();

    const int t = threadIdx.x;
    if (t < 128) {
        float m = sm[0][t];
        #pragma unroll
        for (int w = 1; w < 8; ++w) m = fminf(m, sm[w][t]);
        atomicMin((unsigned int*)out + half * 128 + t, __float_as_uint(m));
    }
}

extern "C" void kernel_launch(void* const* d_in, const int* in_sizes, int n_in,
                              void* d_out, int out_size, void* d_ws, size_t ws_size,
                              hipStream_t stream) {
    const float* input   = (const float*)d_in[0];
    const int*   lit_idx = (const int*)d_in[1];
    const int*   lit_neg = (const int*)d_in[2];
    float*       out     = (float*)d_out;

    half4_t* input16 = (half4_t*)d_ws;  // 5.12 MB << ws_size; fill is free

    fuzzy_convert_init<<<1024, 256, 0, stream>>>((const float4_t*)input,
                                                 input16, out);
    fuzzy_cnf_fp16<<<512, 512, 0, stream>>>((const half2_t*)input16,
                                            lit_idx, lit_neg, out);
}

// Round 5
// 81.667 us; speedup vs baseline: 1.0236x; 1.0236x over previous
//
#include <hip/hip_runtime.h>
#include <hip/hip_fp16.h>

#define NUM_VARS    10000
#define NUM_CLAUSES 100000
#define BATCH       256
#define SLAB        200     // clauses per block: 500 slabs x 2 halves = 1000 blocks, exact
#define CPW         25      // clauses per wave (8 waves x 25 = 200)
#define CPI         4       // clauses per pipeline chunk (12 gathers/bank)
#define NCH         6       // full chunks per wave (24 clauses) + 1 tail clause
#define LDS_W       76      // ints per wave metadata segment (304B, 16B-aligned)

typedef __attribute__((ext_vector_type(4))) _Float16 half4_t;
typedef __attribute__((ext_vector_type(2))) _Float16 half2_t;
typedef __attribute__((ext_vector_type(4))) float    float4_t;
typedef __attribute__((ext_vector_type(4))) int      int4_t;

static __device__ __forceinline__ half2_t h2max(half2_t a, half2_t b) {
    half2_t r;                       // v_pk_max_f16 (no NaN in this data)
    r.x = (a.x > b.x) ? a.x : b.x;
    r.y = (a.y > b.y) ? a.y : b.y;
    return r;
}
static __device__ __forceinline__ half2_t h2min(half2_t a, half2_t b) {
    half2_t r;                       // v_pk_min_f16
    r.x = (a.x < b.x) ? a.x : b.x;
    r.y = (a.y < b.y) ? a.y : b.y;
    return r;
}

// Pipeline bank: one chunk's packed metadata (pk = idx<<1 | neg) + gather data.
// 12 + 12 = 24 VGPR per bank; two banks + misc ~= 56 VGPR total.
struct Bank { int pk[12]; half2_t g[12]; };

// Broadcast ds_read_b128 x3: wl is the wave's 16B-aligned LDS segment,
// intOff is a multiple of 12 (48B) -> every read 16B-aligned.
static __device__ __forceinline__ void ldsMeta(Bank& b, const int* wl, int intOff) {
    const int4_t* p = (const int4_t*)(wl + intOff);
    const int4_t a = p[0], c = p[1], d = p[2];
    b.pk[0]=a.x; b.pk[1]=a.y; b.pk[2]=a.z;  b.pk[3]=a.w;
    b.pk[4]=c.x; b.pk[5]=c.y; b.pk[6]=c.z;  b.pk[7]=c.w;
    b.pk[8]=d.x; b.pk[9]=d.y; b.pk[10]=d.z; b.pk[11]=d.w;
}

// Issue all 12 gathers of a bank: byte offset = idx*512 + coffB, saddr-form
// global_load_dword (256B/wave, L2-resident: 2.56MB/half < 4MiB per-XCD L2).
static __device__ __forceinline__ void issueG(Bank& b, const char* inB, int coffB) {
    #pragma unroll
    for (int j = 0; j < 12; ++j) {
        const unsigned vb = ((unsigned)(b.pk[j] & ~1) << 8) + coffB;
        b.g[j] = *(const half2_t*)(inB + vb);
    }
}

// neg ? 1-x : x  ==  s*x + n with s=1-2n: one v_pk_fma_f16 per literal after
// two cndmasks off the packed neg bit.
static __device__ __forceinline__ void computeC(const Bank& b, half2_t& acc,
        half2_t one2, half2_t mone2, half2_t zero2) {
    #pragma unroll
    for (int q = 0; q < CPI; ++q) {
        half2_t v[3];
        #pragma unroll
        for (int l = 0; l < 3; ++l) {
            const int j = 3 * q + l;
            const bool neg = b.pk[j] & 1;
            const half2_t sv = neg ? mone2 : one2;
            const half2_t nv = neg ? one2  : zero2;
            v[l] = b.g[j] * sv + nv;           // v_pk_fma_f16
        }
        acc = h2min(acc, h2max(h2max(v[0], v[1]), v[2]));
    }
}

// Kernel 1: fp32 -> fp16 convert into d_ws + init d_out to +inf.
// The harness's 256 MiB ws poison fill is UNCONDITIONAL (r1/r2: fills ran
// at ~41us/call with ws untouched), so using ws costs nothing extra.
__global__ __launch_bounds__(256) void fuzzy_convert_init(
    const float4_t* __restrict__ in,    // [NUM_VARS*BATCH/4] fp32
    half4_t*        __restrict__ out16, // same linear layout, fp16
    float*          __restrict__ out)   // [BATCH]
{
    if (blockIdx.x == 0 && threadIdx.x < BATCH)
        out[threadIdx.x] = __uint_as_float(0x7F800000u);  // +inf

    const int n4 = NUM_VARS * BATCH / 4;  // 640000
    for (int i = blockIdx.x * blockDim.x + threadIdx.x; i < n4;
         i += gridDim.x * blockDim.x) {
        float4_t v = in[i];
        half4_t h;
        h.x = (_Float16)v.x;  h.y = (_Float16)v.y;
        h.z = (_Float16)v.z;  h.w = (_Float16)v.w;
        out16[i] = h;
    }
}

// r2-r4 lesson: cnf time (~20-25us inferred) was invariant to halving gather
// bytes AND gather instruction count -> bottleneck is the per-chunk scalar
// metadata latency chain (L3 s_loads, 1-deep prefetch), not BW/issue.
// This version loads each block's 200-clause metadata ONCE, coalesced, into
// LDS (packed idx<<1|neg), then runs a 6-deep gather pipeline per wave with
// broadcast ds_read_b128 metadata reads. Batch-half split via XCD steering
// (xcd 0-3 -> cols 0-127, 4-7 -> 128-255) keeps gathers per-XCD-L2-resident.
__global__ __launch_bounds__(512, 6) void fuzzy_cnf_fp16(
    const half2_t* __restrict__ input16,  // [NUM_VARS, 128] half2
    const int*     __restrict__ lit_idx,  // [NUM_CLAUSES, 3]
    const int*     __restrict__ lit_neg,  // [NUM_CLAUSES, 3]
    float*         __restrict__ out)      // [BATCH]
{
    __shared__ __align__(16) int lds_pk[8 * LDS_W];   // 2432 B
    __shared__ float sm[8][128];

    const int wave   = threadIdx.x >> 6;              // 0..7
    const int lane   = threadIdx.x & 63;
    const int xcd    = blockIdx.x & 7;                // round-robin heuristic
    const int half   = (xcd >= 4) ? 1 : 0;            // batch half
    const int hBlock = ((blockIdx.x >> 3) << 2) | (xcd & 3);   // 0..499 exact
    const int coffB  = (half * 64 + lane) * 4;        // byte column offset

    // Cooperative coalesced metadata load + pack: slab = 200 clauses.
    const int base = hBlock * (SLAB * 3);
    for (int t = threadIdx.x; t < SLAB * 3; t += 512) {
        const int c  = t / 3;                 // clause within slab
        const int r  = t - c * 3;             // literal slot
        const int w  = c / CPW;               // owning wave
        const int lc = c - w * CPW;           // clause within wave
        lds_pk[w * LDS_W + lc * 3 + r] = (lit_idx[base + t] << 1) | lit_neg[base + t];
    }
    __syncthreads();

    const int*  wl  = lds_pk + wave * LDS_W;
    const char* inB = (const char*)input16;

    half2_t one2, mone2, zero2;
    one2.x  = (_Float16) 1.0f;  one2.y  = (_Float16) 1.0f;
    mone2.x = (_Float16)-1.0f;  mone2.y = (_Float16)-1.0f;
    zero2.x = (_Float16) 0.0f;  zero2.y = (_Float16) 0.0f;

    half2_t acc;
    acc.x = (_Float16)30000.0f;  acc.y = (_Float16)30000.0f;

    // 6-deep static pipeline over 24 clauses (chunks of 4), then 1 tail clause.
    Bank A, B;
    ldsMeta(A, wl, 0);  issueG(A, inB, coffB);        // chunk 0 in flight
    ldsMeta(B, wl, 12); issueG(B, inB, coffB);        // chunk 1 in flight

    #pragma unroll
    for (int k = 0; k < NCH - 2; ++k) {               // k = 0..3, parity-folded
        Bank& done = (k & 1) ? B : A;
        computeC(done, acc, one2, mone2, zero2);      // waits only its 12 loads
        ldsMeta(done, wl, (k + 2) * 12);              // refill freed bank
        issueG(done, inB, coffB);
    }
    computeC(A, acc, one2, mone2, zero2);             // chunk 4 (banked in A)
    computeC(B, acc, one2, mone2, zero2);             // chunk 5 (banked in B)

    {   // tail clause 24: ints [72,75)
        Bank T;
        T.pk[0] = wl[72]; T.pk[1] = wl[73]; T.pk[2] = wl[74];
        #pragma unroll
        for (int j = 0; j < 3; ++j) {
            const unsigned vb = ((unsigned)(T.pk[j] & ~1) << 8) + coffB;
            T.g[j] = *(const half2_t*)(inB + vb);
        }
        half2_t v[3];
        #pragma unroll
        for (int l = 0; l < 3; ++l) {
            const bool neg = T.pk[l] & 1;
            const half2_t sv = neg ? mone2 : one2;
            const half2_t nv = neg ? one2  : zero2;
            v[l] = T.g[l] * sv + nv;
        }
        acc = h2min(acc, h2max(h2max(v[0], v[1]), v[2]));
    }

    // 8 waves -> partial min per column in LDS, then one device atomicMin per
    // column per block (values >= 0 so float-bit order == uint order).
    sm[wave][lane * 2 + 0] = (float)acc.x;
    sm[wave][lane * 2 + 1] = (float)acc.y;
    __syncthreads();

    const int t = threadIdx.x;
    if (t < 128) {
        float m = sm[0][t];
        #pragma unroll
        for (int w = 1; w < 8; ++w) m = fminf(m, sm[w][t]);
        atomicMin((unsigned int*)out + half * 128 + t, __float_as_uint(m));
    }
}

extern "C" void kernel_launch(void* const* d_in, const int* in_sizes, int n_in,
                              void* d_out, int out_size, void* d_ws, size_t ws_size,
                              hipStream_t stream) {
    const float* input   = (const float*)d_in[0];
    const int*   lit_idx = (const int*)d_in[1];
    const int*   lit_neg = (const int*)d_in[2];
    float*       out     = (float*)d_out;

    half4_t* input16 = (half4_t*)d_ws;  // 5.12 MB << ws_size; fill is free

    fuzzy_convert_init<<<1024, 256, 0, stream>>>((const float4_t*)input,
                                                 input16, out);
    fuzzy_cnf_fp16<<<1000, 512, 0, stream>>>((const half2_t*)input16,
                                             lit_idx, lit_neg, out);
}